// Round 23
// baseline (28.719 us; speedup 1.0000x reference)
//
#include <hip/hip_runtime.h>

#define N 384
#define DXD 128
#define DZD 32
#define NPAIR 192                  // pairs of 2 b's per matrix (whole row)
#define NORM (2.0f / 1443840.0f)   // 2 / (n*K*(2n-3K-1)), n=384, K=5
#define CX 24.0f                   // exponent centers (cancel in sigma ratio)
#define CZ 12.0f

typedef float f32x2 __attribute__((ext_vector_type(2)));

#define PKFMA(d, a, b, c) asm("v_pk_fma_f32 %0, %1, %2, %3" : "=v"(d) : "v"(a), "v"(b), "v"(c))
#define PKADD(d, a, b)    asm("v_pk_add_f32 %0, %1, %2"     : "=v"(d) : "v"(a), "v"(b))
#define PKMUL(d, a, b)    asm("v_pk_mul_f32 %0, %1, %2"     : "=v"(d) : "v"(a), "v"(b))

// ---------------------------------------------------------------------------
// Kernel 1: Gram matrices. Blocks 0..143: GX = X X^T tile (32x32, K=128);
// blocks 144..287: GZ (K=32). Norms from the diagonal (same rounding as G).
// Also zeroes out[0] (stream-ordered before fused_loss atomics).
__global__ void __launch_bounds__(256) gram(const float* __restrict__ X,
                                            const float* __restrict__ Z,
                                            float* __restrict__ GX,
                                            float* __restrict__ GZ,
                                            float* __restrict__ NX,
                                            float* __restrict__ NZ,
                                            float* __restrict__ out) {
    __shared__ float As[32][132];   // +4 pad: bank-spread, 16B-aligned rows
    __shared__ float Bs[32][132];
    const int b = blockIdx.x;
    const int t = threadIdx.x;
    if (b == 0 && t == 0) out[0] = 0.f;

    const bool isX = (b < 144);
    const int bb = isX ? b : b - 144;
    const int bi = bb / 12, bj = bb % 12;
    const int R = bi * 32, C = bj * 32;
    const float* __restrict__ A = isX ? X : Z;
    const int K = isX ? DXD : DZD;
    float* __restrict__ G = isX ? GX : GZ;
    float* __restrict__ Nv = isX ? NX : NZ;

    const int kf4 = K / 4;                 // 32 (X) or 8 (Z)
    const int nf4 = 32 * kf4;              // 1024 or 256
    for (int idx = t; idx < nf4; idx += 256) {
        const int r = idx / kf4;
        const int c4 = (idx % kf4) * 4;
        float4 va = *reinterpret_cast<const float4*>(A + (size_t)(R + r) * K + c4);
        float4 vb = *reinterpret_cast<const float4*>(A + (size_t)(C + r) * K + c4);
        *reinterpret_cast<float4*>(&As[r][c4]) = va;
        *reinterpret_cast<float4*>(&Bs[r][c4]) = vb;
    }
    __syncthreads();

    const int ty = t >> 4, tx = t & 15;
    const int r0 = 2 * ty, c0 = 2 * tx;
    float a00 = 0.f, a01 = 0.f, a10 = 0.f, a11 = 0.f;
    for (int k = 0; k < K; k += 4) {
        float4 ar0 = *reinterpret_cast<const float4*>(&As[r0][k]);
        float4 ar1 = *reinterpret_cast<const float4*>(&As[r0 + 1][k]);
        float4 bc0 = *reinterpret_cast<const float4*>(&Bs[c0][k]);
        float4 bc1 = *reinterpret_cast<const float4*>(&Bs[c0 + 1][k]);
        a00 += ar0.x * bc0.x + ar0.y * bc0.y + ar0.z * bc0.z + ar0.w * bc0.w;
        a01 += ar0.x * bc1.x + ar0.y * bc1.y + ar0.z * bc1.z + ar0.w * bc1.w;
        a10 += ar1.x * bc0.x + ar1.y * bc0.y + ar1.z * bc0.z + ar1.w * bc0.w;
        a11 += ar1.x * bc1.x + ar1.y * bc1.y + ar1.z * bc1.z + ar1.w * bc1.w;
    }
    float2 w0; w0.x = a00; w0.y = a01;
    float2 w1; w1.x = a10; w1.y = a11;
    *reinterpret_cast<float2*>(G + (size_t)(R + r0) * N + C + c0) = w0;
    *reinterpret_cast<float2*>(G + (size_t)(R + r0 + 1) * N + C + c0) = w1;
    if (R == C && r0 == c0) {              // diagonal: same value, same rounding
        Nv[R + r0] = a00;
        Nv[R + r0 + 1] = a11;
    }
}

// ---------------------------------------------------------------------------
// Kernel 2: fused loss, HIGH-OCCUPANCY: 768 blocks x 384 threads (6 waves)
// = 3 blocks/CU = 18 waves/CU (4.5/SIMD), double R22's residency.
// Block (i = bid>>1, half): a in [half*192, half*192+192), all 384 b.
// Phase 1: full e-table, ONE Gram-based entry per thread (cheap).
// Phase 1.5: pair table ps[p] = (Px,Pz,Sx,Sz) (threads 0..191).
// Phase 2: thread (qh = t/48 -> 8 windows x 24 pairs, tt = t%48) handles
// quad-a {tt, tt+48, tt+96, tt+144} over window qh: 48 UNITs/thread.
// Phase 3: combine 8 windows per a, nonlinearity, reduce, one atomic.
__global__ void __launch_bounds__(384, 5) fused_loss(const float* __restrict__ GX,
                                                     const float* __restrict__ GZ,
                                                     const float* __restrict__ NX,
                                                     const float* __restrict__ NZ,
                                                     float* __restrict__ out) {
    __shared__ float ex[N] __attribute__((aligned(16)));
    __shared__ float ez[N] __attribute__((aligned(16)));
    __shared__ float4 ps[NPAIR];
    __shared__ float sxp[8][192];
    __shared__ float szp[8][192];
    __shared__ float red[3];
    const int i = blockIdx.x >> 1;
    const int half = blockIdx.x & 1;
    const int t = threadIdx.x;

    // phase 1: one e-table entry per thread (a = t)
    {
        const float nxi = NX[i];           // uniform -> scalar path
        const float nzi = NZ[i];
        float gx = GX[(size_t)i * N + t];  // coalesced
        float d2x = fmaxf(nxi + NX[t] - 2.f * gx, 0.f);
        float dx = (d2x > 1e-12f) ? sqrtf(d2x) : 0.f;
        ex[t] = __expf(2.f * dx - CX);

        float gz = GZ[(size_t)i * N + t];
        float d2z = fmaxf(nzi + NZ[t] - 2.f * gz, 0.f);
        float dz = (d2z > 1e-12f) ? sqrtf(d2z) : 0.f;
        ez[t] = __expf(2.f * dz - CZ);
    }
    __syncthreads();

    // phase 1.5: pair table (stride-2 reads = 2-way alias, free)
    if (t < NPAIR) {
        float e0 = ex[2 * t], e1 = ex[2 * t + 1];
        float f0 = ez[2 * t], f1 = ez[2 * t + 1];
        ps[t] = make_float4(e0 * e1, f0 * f1, e0 + e1, f0 + f1);
    }
    __syncthreads();

    // phase 2: quad-a over this thread's 24-pair window
    const int qh = t / 48;             // 0..7 (wave spans 2 windows: 2-way bcast)
    const int tt = t - 48 * qh;        // 0..47
    const int a0 = half * 192 + tt;
    const int a1 = a0 + 48, a2 = a0 + 96, a3 = a0 + 144;

    f32x2 ee0;  ee0.x = ex[a0]; ee0.y = ez[a0];
    f32x2 ee1;  ee1.x = ex[a1]; ee1.y = ez[a1];
    f32x2 ee2;  ee2.x = ex[a2]; ee2.y = ez[a2];
    f32x2 ee3;  ee3.x = ex[a3]; ee3.y = ez[a3];
    f32x2 eq0, eq1, eq2, eq3;
    PKMUL(eq0, ee0, ee0);
    PKMUL(eq1, ee1, ee1);
    PKMUL(eq2, ee2, ee2);
    PKMUL(eq3, ee3, ee3);

    f32x2 A0 = {0.f, 0.f}, A1 = {0.f, 0.f}, A2 = {0.f, 0.f}, A3 = {0.f, 0.f};

#define UNIT(c0v, c1v, eev, eeq, accm)                                        \
    {                                                                         \
        f32x2 P0; P0.x = c0v.x; P0.y = c0v.y;                                 \
        f32x2 S0; S0.x = c0v.z; S0.y = c0v.w;                                 \
        f32x2 P1; P1.x = c1v.x; P1.y = c1v.y;                                 \
        f32x2 S1; S1.x = c1v.z; S1.y = c1v.w;                                 \
        f32x2 t0, t1, d0, d1, n0, n1, D, T, Nn, r;                            \
        PKFMA(t0, eev, S0, P0);                                               \
        PKFMA(t1, eev, S1, P1);                                               \
        PKADD(d0, t0, eeq);                                                   \
        PKADD(d1, t1, eeq);                                                   \
        PKADD(n0, t0, P0);                                                    \
        PKADD(n1, t1, P1);                                                    \
        PKMUL(D, d0, d1);                                                     \
        PKMUL(T, n0, d1);                                                     \
        PKFMA(Nn, n1, d0, T);                                                 \
        r.x = __builtin_amdgcn_rcpf(D.x);                                     \
        r.y = __builtin_amdgcn_rcpf(D.y);                                     \
        PKFMA(accm, Nn, r, accm);                                             \
    }

    const int p0 = qh * 24;            // this window's 24 pairs = 12 units
    #pragma unroll 3
    for (int p = p0; p < p0 + 24; p += 4) {   // 6 iters x 2 unit positions
        #pragma unroll
        for (int j = 0; j < 2; ++j) {
            float4 c0 = ps[p + 2 * j];        // shared by all 4 a's
            float4 c1 = ps[p + 2 * j + 1];
            UNIT(c0, c1, ee0, eq0, A0)
            UNIT(c0, c1, ee1, eq1, A1)
            UNIT(c0, c1, ee2, eq2, A2)
            UNIT(c0, c1, ee3, eq3, A3)
        }
    }
#undef UNIT

    sxp[qh][tt]       = A0.x;  szp[qh][tt]       = A0.y;
    sxp[qh][tt + 48]  = A1.x;  szp[qh][tt + 48]  = A1.y;
    sxp[qh][tt + 96]  = A2.x;  szp[qh][tt + 96]  = A2.y;
    sxp[qh][tt + 144] = A3.x;  szp[qh][tt + 144] = A3.y;
    __syncthreads();

    // phase 3: threads 0..191 finalize a-slot t of this half
    if (t < 192) {
        float sx = ((sxp[0][t] + sxp[1][t]) + (sxp[2][t] + sxp[3][t]))
                 + ((sxp[4][t] + sxp[5][t]) + (sxp[6][t] + sxp[7][t]));
        float sz = ((szp[0][t] + szp[1][t]) + (szp[2][t] + szp[3][t]))
                 + ((szp[4][t] + szp[5][t]) + (szp[6][t] + szp[7][t]));
        // intrusion = relu(1+sx-K); W = clamp((K+1-(1+sz))/K, 0, 1)
        float intr = fmaxf(sx - 4.f, 0.f);
        float W = fminf(fmaxf((5.f - sz) * 0.2f, 0.f), 1.f);
        float contrib = intr * (1.f - W);
        #pragma unroll
        for (int off = 32; off > 0; off >>= 1)
            contrib += __shfl_down(contrib, off, 64);
        const int lane = t & 63, w = t >> 6;
        if (lane == 0) red[w] = contrib;
    }
    __syncthreads();
    if (t == 0) atomicAdd(out, (red[0] + red[1] + red[2]) * NORM);
}

extern "C" void kernel_launch(void* const* d_in, const int* in_sizes, int n_in,
                              void* d_out, int out_size, void* d_ws, size_t ws_size,
                              hipStream_t stream) {
    const float* X = (const float*)d_in[0];   // (384, 128) f32
    const float* Z = (const float*)d_in[1];   // (384, 32)  f32
    float* out = (float*)d_out;

    float* GX = (float*)d_ws;                  // 384*384
    float* GZ = GX + (size_t)N * N;            // 384*384
    float* NXv = GZ + (size_t)N * N;           // 384
    float* NZv = NXv + N;                      // 384

    gram<<<288, 256, 0, stream>>>(X, Z, GX, GZ, NXv, NZv, out);
    fused_loss<<<2 * N, 384, 0, stream>>>(GX, GZ, NXv, NZv, out);
}

// Round 24
// 26.327 us; speedup vs baseline: 1.0908x; 1.0908x over previous
//
#include <hip/hip_runtime.h>

#define N 384
#define DXD 128
#define DZD 32
#define NPAIR 192                  // pairs of 2 b's per matrix (whole row)
#define NORM (2.0f / 1443840.0f)   // 2 / (n*K*(2n-3K-1)), n=384, K=5
#define CX 24.0f                   // exponent centers (cancel in sigma ratio)
#define CZ 12.0f

typedef float f32x2 __attribute__((ext_vector_type(2)));

#define PKFMA(d, a, b, c) asm("v_pk_fma_f32 %0, %1, %2, %3" : "=v"(d) : "v"(a), "v"(b), "v"(c))
#define PKADD(d, a, b)    asm("v_pk_add_f32 %0, %1, %2"     : "=v"(d) : "v"(a), "v"(b))
#define PKMUL(d, a, b)    asm("v_pk_mul_f32 %0, %1, %2"     : "=v"(d) : "v"(a), "v"(b))

// ---------------------------------------------------------------------------
// Kernel 1: Gram matrices. Blocks 0..143: GX = X X^T tile (32x32, K=128);
// blocks 144..287: GZ (K=32). Norms from the diagonal (same rounding as G).
// Also zeroes out[0] (stream-ordered before fused_loss atomics).
__global__ void __launch_bounds__(256) gram(const float* __restrict__ X,
                                            const float* __restrict__ Z,
                                            float* __restrict__ GX,
                                            float* __restrict__ GZ,
                                            float* __restrict__ NX,
                                            float* __restrict__ NZ,
                                            float* __restrict__ out) {
    __shared__ float As[32][132];   // +4 pad: bank-spread, 16B-aligned rows
    __shared__ float Bs[32][132];
    const int b = blockIdx.x;
    const int t = threadIdx.x;
    if (b == 0 && t == 0) out[0] = 0.f;

    const bool isX = (b < 144);
    const int bb = isX ? b : b - 144;
    const int bi = bb / 12, bj = bb % 12;
    const int R = bi * 32, C = bj * 32;
    const float* __restrict__ A = isX ? X : Z;
    const int K = isX ? DXD : DZD;
    float* __restrict__ G = isX ? GX : GZ;
    float* __restrict__ Nv = isX ? NX : NZ;

    const int kf4 = K / 4;                 // 32 (X) or 8 (Z)
    const int nf4 = 32 * kf4;              // 1024 or 256
    for (int idx = t; idx < nf4; idx += 256) {
        const int r = idx / kf4;
        const int c4 = (idx % kf4) * 4;
        float4 va = *reinterpret_cast<const float4*>(A + (size_t)(R + r) * K + c4);
        float4 vb = *reinterpret_cast<const float4*>(A + (size_t)(C + r) * K + c4);
        *reinterpret_cast<float4*>(&As[r][c4]) = va;
        *reinterpret_cast<float4*>(&Bs[r][c4]) = vb;
    }
    __syncthreads();

    const int ty = t >> 4, tx = t & 15;
    const int r0 = 2 * ty, c0 = 2 * tx;
    float a00 = 0.f, a01 = 0.f, a10 = 0.f, a11 = 0.f;
    for (int k = 0; k < K; k += 4) {
        float4 ar0 = *reinterpret_cast<const float4*>(&As[r0][k]);
        float4 ar1 = *reinterpret_cast<const float4*>(&As[r0 + 1][k]);
        float4 bc0 = *reinterpret_cast<const float4*>(&Bs[c0][k]);
        float4 bc1 = *reinterpret_cast<const float4*>(&Bs[c0 + 1][k]);
        a00 += ar0.x * bc0.x + ar0.y * bc0.y + ar0.z * bc0.z + ar0.w * bc0.w;
        a01 += ar0.x * bc1.x + ar0.y * bc1.y + ar0.z * bc1.z + ar0.w * bc1.w;
        a10 += ar1.x * bc0.x + ar1.y * bc0.y + ar1.z * bc0.z + ar1.w * bc0.w;
        a11 += ar1.x * bc1.x + ar1.y * bc1.y + ar1.z * bc1.z + ar1.w * bc1.w;
    }
    float2 w0; w0.x = a00; w0.y = a01;
    float2 w1; w1.x = a10; w1.y = a11;
    *reinterpret_cast<float2*>(G + (size_t)(R + r0) * N + C + c0) = w0;
    *reinterpret_cast<float2*>(G + (size_t)(R + r0 + 1) * N + C + c0) = w1;
    if (R == C && r0 == c0) {              // diagonal: same value, same rounding
        Nv[R + r0] = a00;
        Nv[R + r0 + 1] = a11;
    }
}

// ---------------------------------------------------------------------------
// Kernel 2: fused loss, balanced grid + quad-a. Block (i = bid>>1, half),
// 192 threads (3 waves) -> 768 blocks = exactly 3/CU.
// Phase 1 (cheap, Gram-based): e[a] = exp(2*sqrt(max(n_i+n_a-2G,0)) - C).
// Phase 1.5: pair table ps[p] = (Px,Pz,Sx,Sz).
// Phase 2: quad-a: thread (qh=t/48, tt=t%48) handles 4 a-slots {tt+48j} of
// this half over b-window qh (48 pairs); each ds_read_b128 feeds 4 UNITs.
// Phase 3: combine 4 windows per a, nonlinearity, reduce, one atomic.
__global__ void __launch_bounds__(192) fused_loss(const float* __restrict__ GX,
                                                  const float* __restrict__ GZ,
                                                  const float* __restrict__ NX,
                                                  const float* __restrict__ NZ,
                                                  float* __restrict__ out) {
    __shared__ float ex[N] __attribute__((aligned(16)));
    __shared__ float ez[N] __attribute__((aligned(16)));
    __shared__ float4 ps[NPAIR];
    __shared__ float sxp[4][192];
    __shared__ float szp[4][192];
    __shared__ float red[3];
    const int i = blockIdx.x >> 1;
    const int half = blockIdx.x & 1;
    const int t = threadIdx.x;

    // phase 1: full e-tables from Gram rows (entries t and t+192)
    const float nxi = NX[i];               // uniform -> scalar path
    const float nzi = NZ[i];
    #pragma unroll
    for (int rep = 0; rep < 2; ++rep) {
        const int a = rep * 192 + t;
        float gx = GX[(size_t)i * N + a];  // coalesced
        float d2x = fmaxf(nxi + NX[a] - 2.f * gx, 0.f);
        float dx = (d2x > 1e-12f) ? sqrtf(d2x) : 0.f;
        ex[a] = __expf(2.f * dx - CX);

        float gz = GZ[(size_t)i * N + a];
        float d2z = fmaxf(nzi + NZ[a] - 2.f * gz, 0.f);
        float dz = (d2z > 1e-12f) ? sqrtf(d2z) : 0.f;
        ez[a] = __expf(2.f * dz - CZ);
    }
    __syncthreads();

    // phase 1.5: pair table (stride-2 reads = 2-way alias, free)
    {
        float e0 = ex[2 * t], e1 = ex[2 * t + 1];
        float f0 = ez[2 * t], f1 = ez[2 * t + 1];
        ps[t] = make_float4(e0 * e1, f0 * f1, e0 + e1, f0 + f1);
    }
    __syncthreads();

    // phase 2: quad-a over this thread's 48-pair window
    const int qh = t / 48;             // 0..3 (2 windows per wave: 2-way bcast)
    const int tt = t - 48 * qh;        // 0..47
    const int a0 = half * 192 + tt;
    const int a1 = a0 + 48, a2 = a0 + 96, a3 = a0 + 144;

    f32x2 ee0;  ee0.x = ex[a0]; ee0.y = ez[a0];
    f32x2 ee1;  ee1.x = ex[a1]; ee1.y = ez[a1];
    f32x2 ee2;  ee2.x = ex[a2]; ee2.y = ez[a2];
    f32x2 ee3;  ee3.x = ex[a3]; ee3.y = ez[a3];
    f32x2 eq0, eq1, eq2, eq3;
    PKMUL(eq0, ee0, ee0);
    PKMUL(eq1, ee1, ee1);
    PKMUL(eq2, ee2, ee2);
    PKMUL(eq3, ee3, ee3);

    f32x2 A0 = {0.f, 0.f}, A1 = {0.f, 0.f}, A2 = {0.f, 0.f}, A3 = {0.f, 0.f};

#define UNIT(c0v, c1v, eev, eeq, accm)                                        \
    {                                                                         \
        f32x2 P0; P0.x = c0v.x; P0.y = c0v.y;                                 \
        f32x2 S0; S0.x = c0v.z; S0.y = c0v.w;                                 \
        f32x2 P1; P1.x = c1v.x; P1.y = c1v.y;                                 \
        f32x2 S1; S1.x = c1v.z; S1.y = c1v.w;                                 \
        f32x2 t0, t1, d0, d1, n0, n1, D, T, Nn, r;                            \
        PKFMA(t0, eev, S0, P0);                                               \
        PKFMA(t1, eev, S1, P1);                                               \
        PKADD(d0, t0, eeq);                                                   \
        PKADD(d1, t1, eeq);                                                   \
        PKADD(n0, t0, P0);                                                    \
        PKADD(n1, t1, P1);                                                    \
        PKMUL(D, d0, d1);                                                     \
        PKMUL(T, n0, d1);                                                     \
        PKFMA(Nn, n1, d0, T);                                                 \
        r.x = __builtin_amdgcn_rcpf(D.x);                                     \
        r.y = __builtin_amdgcn_rcpf(D.y);                                     \
        PKFMA(accm, Nn, r, accm);                                             \
    }

    const int p0 = qh * 48;            // this window's 48 pairs = 24 units
    #pragma unroll 3
    for (int p = p0; p < p0 + 48; p += 4) {   // 12 iters x 2 unit positions
        #pragma unroll
        for (int j = 0; j < 2; ++j) {
            float4 c0 = ps[p + 2 * j];        // shared by all 4 a's
            float4 c1 = ps[p + 2 * j + 1];
            UNIT(c0, c1, ee0, eq0, A0)
            UNIT(c0, c1, ee1, eq1, A1)
            UNIT(c0, c1, ee2, eq2, A2)
            UNIT(c0, c1, ee3, eq3, A3)
        }
    }
#undef UNIT

    sxp[qh][tt]       = A0.x;  szp[qh][tt]       = A0.y;
    sxp[qh][tt + 48]  = A1.x;  szp[qh][tt + 48]  = A1.y;
    sxp[qh][tt + 96]  = A2.x;  szp[qh][tt + 96]  = A2.y;
    sxp[qh][tt + 144] = A3.x;  szp[qh][tt + 144] = A3.y;
    __syncthreads();

    // phase 3: thread t finalizes a-slot t of this half
    {
        float sx = (sxp[0][t] + sxp[1][t]) + (sxp[2][t] + sxp[3][t]);
        float sz = (szp[0][t] + szp[1][t]) + (szp[2][t] + szp[3][t]);
        // intrusion = relu(1+sx-K); W = clamp((K+1-(1+sz))/K, 0, 1)
        float intr = fmaxf(sx - 4.f, 0.f);
        float W = fminf(fmaxf((5.f - sz) * 0.2f, 0.f), 1.f);
        float contrib = intr * (1.f - W);
        #pragma unroll
        for (int off = 32; off > 0; off >>= 1)
            contrib += __shfl_down(contrib, off, 64);
        const int lane = t & 63, w = t >> 6;
        if (lane == 0) red[w] = contrib;
    }
    __syncthreads();
    if (t == 0) atomicAdd(out, (red[0] + red[1] + red[2]) * NORM);
}

extern "C" void kernel_launch(void* const* d_in, const int* in_sizes, int n_in,
                              void* d_out, int out_size, void* d_ws, size_t ws_size,
                              hipStream_t stream) {
    const float* X = (const float*)d_in[0];   // (384, 128) f32
    const float* Z = (const float*)d_in[1];   // (384, 32)  f32
    float* out = (float*)d_out;

    float* GX = (float*)d_ws;                  // 384*384
    float* GZ = GX + (size_t)N * N;            // 384*384
    float* NXv = GZ + (size_t)N * N;           // 384
    float* NZv = NXv + N;                      // 384

    gram<<<288, 256, 0, stream>>>(X, Z, GX, GZ, NXv, NZv, out);
    fused_loss<<<2 * N, 192, 0, stream>>>(GX, GZ, NXv, NZv, out);
}